// Round 2
// baseline (597.133 us; speedup 1.0000x reference)
//
#include <hip/hip_runtime.h>

typedef unsigned short u16;
typedef unsigned int u32;
typedef short s16x8 __attribute__((ext_vector_type(8)));
typedef float f32x4 __attribute__((ext_vector_type(4)));

#define ATTN_SCALE 0.17677669529663687f

__device__ __forceinline__ u16 f2bf(float f) {
  union { float f; u32 i; } c; c.f = f;
  u32 r = c.i + 0x7fffu + ((c.i >> 16) & 1u);
  return (u16)(r >> 16);
}
__device__ __forceinline__ float bf2f(u16 u) {
  union { u32 i; float f; } c; c.i = ((u32)u) << 16; return c.f;
}
__device__ __forceinline__ f32x4 mfma16(s16x8 a, s16x8 b, f32x4 c) {
  return __builtin_amdgcn_mfma_f32_16x16x32_bf16(a, b, c, 0, 0, 0);
}

typedef __attribute__((address_space(1))) u32 gas_u32;
typedef __attribute__((address_space(3))) u32 las_u32;
#define GLL16(gp, lp) __builtin_amdgcn_global_load_lds((gas_u32*)(gp), (las_u32*)(lp), 16, 0, 0)

// window-order token m -> original token index (same formula forward+reverse
// since roll(-3) partition and roll(+3) reverse both reduce to (p+3)%56).
__device__ __forceinline__ int win_to_orig(int m) {
  int b = m / 3136, rem = m - b * 3136;
  int w = rem / 49, n = rem - w * 49;
  int wh = w >> 3, ww = w & 7;
  int i = n / 7, j = n - i * 7;
  int r = wh * 7 + i + 3; if (r >= 56) r -= 56;
  int c = ww * 7 + j + 3; if (c >= 56) c -= 56;
  return b * 3136 + r * 56 + c;
}

// ---------------- fp32 -> bf16 weight conversion ---------------------------
__global__ __launch_bounds__(256) void cvt_kernel(
    const float* __restrict__ in, u16* __restrict__ out, int n) {
  int i = blockIdx.x * 256 + threadIdx.x;
  if (i < n) out[i] = f2bf(in[i]);
}

// ---------------- LayerNorm (fp32 in, bf16 out) ----------------------------
// PERM=true: output token t (window order) <- LN(x[win_to_orig(t)])  (LN1)
// PERM=false: identity order                                         (LN2)
template <bool PERM>
__global__ __launch_bounds__(256) void ln_kernel(
    const float* __restrict__ x, const float* __restrict__ g,
    const float* __restrict__ bb, u16* __restrict__ xo) {
  int t = blockIdx.x * 4 + (threadIdx.x >> 6);
  int l = threadIdx.x & 63;
  int src = PERM ? win_to_orig(t) : t;
  const float* row = x + (size_t)src * 384;
  float v[6];
#pragma unroll
  for (int k = 0; k < 6; k++) v[k] = row[l + 64 * k];
  float s = 0.f;
#pragma unroll
  for (int k = 0; k < 6; k++) s += v[k];
#pragma unroll
  for (int d = 1; d < 64; d <<= 1) s += __shfl_xor(s, d);
  float mean = s * (1.f / 384.f);
  float q = 0.f;
#pragma unroll
  for (int k = 0; k < 6; k++) { float dv = v[k] - mean; q += dv * dv; }
#pragma unroll
  for (int d = 1; d < 64; d <<= 1) q += __shfl_xor(q, d);
  float rstd = rsqrtf(q * (1.f / 384.f) + 1e-5f);
  u16* orow = xo + (size_t)t * 384;
#pragma unroll
  for (int k = 0; k < 6; k++) {
    int c = l + 64 * k;
    orow[c] = f2bf((v[k] - mean) * rstd * g[c] + bb[c]);
  }
}

// ---------------- generic 128x128 BK=32 bf16 GEMM, B^T weights -------------
// EPI 0: +bias -> bf16                   (qkv)
// EPI 1: +bias +x[perm] -> f32 at permuted row (proj + shortcut)
// EPI 2: +bias, exact GELU -> bf16       (fc1)
// EPI 3: +bias +xres -> f32              (fc2 + residual, final output)
template <int EPI>
__global__ __launch_bounds__(256) void gemm_kernel(
    const u16* __restrict__ A, const u16* __restrict__ W,
    const float* __restrict__ bias, u16* __restrict__ outb,
    float* __restrict__ outf, const float* __restrict__ auxf,
    int K, int N, int NT) {
  __shared__ __align__(16) short As[4096];
  __shared__ __align__(16) short Bs[4096];
  const int tid = threadIdx.x, wv = tid >> 6, l = tid & 63;
  const int lr = l & 15, lg = l >> 4;
  const int bm = blockIdx.x / NT, bn = blockIdx.x - bm * NT;
  const size_t m0 = (size_t)bm * 128, n0 = (size_t)bn * 128;
  // staging: lane l writes LDS shorts [wv*512 + l*8, +8) -> (row=wv*16+(l>>2),
  // chunk=l&3). Source chunk XOR-swizzled by ((row>>1)&3) so the fragment
  // reads below are bank-conflict-reduced; LDS dest stays linear (m173).
  const int prow = wv * 16 + (l >> 2);
  const int ccl = (((l & 3) ^ ((l >> 3) & 3)) << 3);
  const u16* ga0 = A + (m0 + prow) * K + ccl;
  const u16* ga1 = A + (m0 + 64 + prow) * K + ccl;
  const u16* gb0 = W + (n0 + prow) * K + ccl;
  const u16* gb1 = W + (n0 + 64 + prow) * K + ccl;
  short* la0 = As + wv * 512;
  short* la1 = As + 2048 + wv * 512;
  short* lb0 = Bs + wv * 512;
  short* lb1 = Bs + 2048 + wv * 512;
  const int wr = wv >> 1, wc = wv & 1;
  const int sw = (lr >> 1) & 3;  // read-side swizzle: (row>>1)&3 == (lr>>1)&3
  f32x4 acc[4][4] = {};
  for (int k0 = 0; k0 < K; k0 += 32) {
    __syncthreads();
    GLL16(ga0 + k0, la0);
    GLL16(ga1 + k0, la1);
    GLL16(gb0 + k0, lb0);
    GLL16(gb1 + k0, lb1);
    __syncthreads();
    s16x8 af[4], bfr[4];
#pragma unroll
    for (int mi = 0; mi < 4; mi++)
      af[mi] = *(const s16x8*)&As[(wr * 64 + mi * 16 + lr) * 32 + ((lg ^ sw) << 3)];
#pragma unroll
    for (int ni = 0; ni < 4; ni++)
      bfr[ni] = *(const s16x8*)&Bs[(wc * 64 + ni * 16 + lr) * 32 + ((lg ^ sw) << 3)];
#pragma unroll
    for (int mi = 0; mi < 4; mi++)
#pragma unroll
      for (int ni = 0; ni < 4; ni++)
        acc[mi][ni] = mfma16(af[mi], bfr[ni], acc[mi][ni]);
  }
  const int colb = (int)n0 + wc * 64;
#pragma unroll
  for (int mi = 0; mi < 4; mi++) {
#pragma unroll
    for (int r = 0; r < 4; r++) {
      const size_t m = m0 + wr * 64 + mi * 16 + lg * 4 + r;
      int dst = 0;
      if (EPI == 1) dst = win_to_orig((int)m);
#pragma unroll
      for (int ni = 0; ni < 4; ni++) {
        const int col = colb + ni * 16 + lr;
        float v = acc[mi][ni][r] + bias[col];
        if (EPI == 0) {
          outb[m * (size_t)N + col] = f2bf(v);
        } else if (EPI == 1) {
          outf[(size_t)dst * 384 + col] = v + auxf[(size_t)dst * 384 + col];
        } else if (EPI == 2) {
          float gl = 0.5f * v * (1.0f + erff(v * 0.70710678118654752f));
          outb[m * (size_t)N + col] = f2bf(gl);
        } else {
          outf[m * (size_t)N + col] = v + auxf[m * (size_t)N + col];
        }
      }
    }
  }
}

// ---------------- windowed attention: 1 wave per (window, head) ------------
__global__ __launch_bounds__(256) void attn_kernel(
    const u16* __restrict__ qkv, const float* __restrict__ rpb,
    const float* __restrict__ maskp, u16* __restrict__ out) {
  __shared__ __align__(16) short Pl[4][64 * 72];   // per-wave P (stride 72)
  __shared__ __align__(16) short Vt[4][32 * 72];   // per-wave V^T (stride 72)
  __shared__ float rpbs[169 * 12];
  const int tid = threadIdx.x, wv = tid >> 6, l = tid & 63;
  const int lr = l & 15, lg = l >> 4;
  for (int idx = tid; idx < 169 * 12; idx += 256) rpbs[idx] = rpb[idx];
  short* vt = Vt[wv];
  for (int idx = l; idx < 32 * 72; idx += 64) vt[idx] = 0;
  __syncthreads();

  const int task = blockIdx.x * 4 + wv;          // < 12288 exactly
  const int win = task / 12, h = task - win * 12;
  const int wi = win & 63;
  const short* base = (const short*)qkv + (size_t)win * 49 * 1152 + h * 32;

  // Q/K fragments (A-lane row = l&15, k-chunk = l>>4; rows >=49 zeroed)
  s16x8 qf[4], kf[4];
  const s16x8 zz = {0, 0, 0, 0, 0, 0, 0, 0};
#pragma unroll
  for (int mi = 0; mi < 4; mi++) {
    int n = mi * 16 + lr;
    if (n < 49) {
      qf[mi] = *(const s16x8*)(base + (size_t)n * 1152 + lg * 8);
      kf[mi] = *(const s16x8*)(base + (size_t)n * 1152 + 384 + lg * 8);
    } else { qf[mi] = zz; kf[mi] = zz; }
  }
  // stage V^T into LDS
  for (int idx = l; idx < 49 * 32; idx += 64) {
    int j = idx >> 5, d = idx & 31;
    vt[d * 72 + j] = base[(size_t)j * 1152 + 768 + d];
  }

  // S = Q K^T (padded 64x64), K=32 in one MFMA step
  f32x4 acc[4][4] = {};
#pragma unroll
  for (int mi = 0; mi < 4; mi++)
#pragma unroll
    for (int ni = 0; ni < 4; ni++)
      acc[mi][ni] = mfma16(qf[mi], kf[ni], acc[mi][ni]);

  // scale + rel-pos bias + shift mask, row softmax; write P (bf16) to LDS
  float rs[4][4];
  short* pl = Pl[wv];
#pragma unroll
  for (int mi = 0; mi < 4; mi++) {
#pragma unroll
    for (int r = 0; r < 4; r++) {
      const int irow = mi * 16 + lg * 4 + r;
      float sv[4];
#pragma unroll
      for (int ni = 0; ni < 4; ni++) {
        const int j = ni * 16 + lr;
        float sval;
        if (irow < 49 && j < 49) {
          int yi = irow / 7, xi = irow - yi * 7;
          int yj = j / 7, xj = j - yj * 7;
          int rpi = (yi - yj + 6) * 13 + (xi - xj + 6);
          sval = acc[mi][ni][r] * ATTN_SCALE + rpbs[rpi * 12 + h] +
                 maskp[(wi * 49 + irow) * 49 + j];
        } else {
          sval = -1e30f;
        }
        sv[ni] = sval;
      }
      float mx = fmaxf(fmaxf(sv[0], sv[1]), fmaxf(sv[2], sv[3]));
#pragma unroll
      for (int d = 1; d < 16; d <<= 1) mx = fmaxf(mx, __shfl_xor(mx, d));
      float sm = 0.f;
#pragma unroll
      for (int ni = 0; ni < 4; ni++) { sv[ni] = __expf(sv[ni] - mx); sm += sv[ni]; }
#pragma unroll
      for (int d = 1; d < 16; d <<= 1) sm += __shfl_xor(sm, d);
      rs[mi][r] = 1.f / sm;
#pragma unroll
      for (int ni = 0; ni < 4; ni++)
        pl[irow * 72 + ni * 16 + lr] = (short)f2bf(sv[ni]);
    }
  }

  // O = P V : A from P-LDS, B from V^T-LDS (contiguous 16B frags)
  f32x4 acc2[4][2] = {};
#pragma unroll
  for (int kk = 0; kk < 2; kk++) {
    s16x8 pa[4], vb[2];
#pragma unroll
    for (int mi = 0; mi < 4; mi++)
      pa[mi] = *(const s16x8*)&pl[(mi * 16 + lr) * 72 + kk * 32 + lg * 8];
#pragma unroll
    for (int nd = 0; nd < 2; nd++)
      vb[nd] = *(const s16x8*)&vt[(nd * 16 + lr) * 72 + kk * 32 + lg * 8];
#pragma unroll
    for (int mi = 0; mi < 4; mi++)
#pragma unroll
      for (int nd = 0; nd < 2; nd++)
        acc2[mi][nd] = mfma16(pa[mi], vb[nd], acc2[mi][nd]);
  }

  // normalize rows by 1/sum and store (head-interleaved channels)
#pragma unroll
  for (int mi = 0; mi < 4; mi++)
#pragma unroll
    for (int r = 0; r < 4; r++) {
      const int irow = mi * 16 + lg * 4 + r;
      if (irow < 49) {
#pragma unroll
        for (int nd = 0; nd < 2; nd++) {
          float o = acc2[mi][nd][r] * rs[mi][r];
          out[((size_t)win * 49 + irow) * 384 + h * 32 + nd * 16 + lr] = f2bf(o);
        }
      }
    }
}

extern "C" void kernel_launch(void* const* d_in, const int* in_sizes, int n_in,
                              void* d_out, int out_size, void* d_ws, size_t ws_size,
                              hipStream_t stream) {
  (void)in_sizes; (void)n_in; (void)out_size; (void)ws_size;
  const float* x     = (const float*)d_in[0];
  const float* maskp = (const float*)d_in[1];
  const float* n1g   = (const float*)d_in[2];
  const float* n1b   = (const float*)d_in[3];
  const float* qkvw  = (const float*)d_in[4];
  const float* qkvb  = (const float*)d_in[5];
  const float* rpb   = (const float*)d_in[6];
  const float* projw = (const float*)d_in[7];
  const float* projb = (const float*)d_in[8];
  const float* n2g   = (const float*)d_in[9];
  const float* n2b   = (const float*)d_in[10];
  const float* fc1w  = (const float*)d_in[11];
  const float* fc1b  = (const float*)d_in[12];
  const float* fc2w  = (const float*)d_in[13];
  const float* fc2b  = (const float*)d_in[14];
  float* outp = (float*)d_out;

  char* ws = (char*)d_ws;
  u16*  regA = (u16*)ws;                           // qkv (50176x1152), then h2 chunks
  u16*  regB = (u16*)(ws + 115605504ull);          // xw / attn_out / xln2 (50176x384)
  float* xres = (float*)(ws + 154140672ull);       // fp32 residual (50176x384)
  u16*  wq = (u16*)(ws + 231211008ull);            // bf16 weights
  u16*  wp = wq + 442368;
  u16*  w1 = wp + 147456;
  u16*  w2 = w1 + 589824;                          // end: 234,749,952 B

  // 0. weights fp32 -> bf16
  cvt_kernel<<<1728, 256, 0, stream>>>(qkvw, wq, 442368);
  cvt_kernel<<<576, 256, 0, stream>>>(projw, wp, 147456);
  cvt_kernel<<<2304, 256, 0, stream>>>(fc1w, w1, 589824);
  cvt_kernel<<<2304, 256, 0, stream>>>(fc2w, w2, 589824);
  // 1. LN1 + cyclic shift + window partition (fp32 -> bf16, window order)
  ln_kernel<true><<<12544, 256, 0, stream>>>(x, n1g, n1b, regB);
  // 2. QKV projection: (50176x384) @ (384x1152)
  gemm_kernel<0><<<392 * 9, 256, 0, stream>>>(regB, wq, qkvb, regA, nullptr,
                                              nullptr, 384, 1152, 9);
  // 3. windowed attention
  attn_kernel<<<3072, 256, 0, stream>>>(regA, rpb, maskp, regB);
  // 4. output projection + shortcut, un-permute -> fp32 residual (orig order)
  gemm_kernel<1><<<392 * 3, 256, 0, stream>>>(regB, wp, projb, nullptr, xres,
                                              x, 384, 384, 3);
  // 5. LN2 (fp32 -> bf16)
  ln_kernel<false><<<12544, 256, 0, stream>>>(xres, n2g, n2b, regB);
  // 6/7. MLP in 2 M-chunks of 25088 rows (h2 reuses dead qkv region)
  for (int c = 0; c < 2; c++) {
    const u16* aln = regB + (size_t)c * 25088 * 384;
    float* oc = outp + (size_t)c * 25088 * 384;
    const float* rc = xres + (size_t)c * 25088 * 384;
    gemm_kernel<2><<<196 * 12, 256, 0, stream>>>(aln, w1, fc1b, regA, nullptr,
                                                 nullptr, 384, 1536, 12);
    gemm_kernel<3><<<196 * 3, 256, 0, stream>>>(regA, w2, fc2b, nullptr, oc,
                                                rc, 1536, 384, 3);
  }
}

// Round 3
// 559.825 us; speedup vs baseline: 1.0666x; 1.0666x over previous
//
#include <hip/hip_runtime.h>

typedef unsigned short u16;
typedef unsigned int u32;
typedef short s16x8 __attribute__((ext_vector_type(8)));
typedef float f32x4 __attribute__((ext_vector_type(4)));

#define ATTN_SCALE 0.17677669529663687f

__device__ __forceinline__ u16 f2bf(float f) {
  union { float f; u32 i; } c; c.f = f;
  u32 r = c.i + 0x7fffu + ((c.i >> 16) & 1u);
  return (u16)(r >> 16);
}
__device__ __forceinline__ float bf2f(u16 u) {
  union { u32 i; float f; } c; c.i = ((u32)u) << 16; return c.f;
}
__device__ __forceinline__ f32x4 mfma16(s16x8 a, s16x8 b, f32x4 c) {
  return __builtin_amdgcn_mfma_f32_16x16x32_bf16(a, b, c, 0, 0, 0);
}

typedef __attribute__((address_space(1))) u32 gas_u32;
typedef __attribute__((address_space(3))) u32 las_u32;
#define GLL16(gp, lp) __builtin_amdgcn_global_load_lds((gas_u32*)(gp), (las_u32*)(lp), 16, 0, 0)

// window-order token m -> original token index (same formula forward+reverse
// since roll(-3) partition and roll(+3) reverse both reduce to (p+3)%56).
__device__ __forceinline__ int win_to_orig(int m) {
  int b = m / 3136, rem = m - b * 3136;
  int w = rem / 49, n = rem - w * 49;
  int wh = w >> 3, ww = w & 7;
  int i = n / 7, j = n - i * 7;
  int r = wh * 7 + i + 3; if (r >= 56) r -= 56;
  int c = ww * 7 + j + 3; if (c >= 56) c -= 56;
  return b * 3136 + r * 56 + c;
}

// ---------------- fp32 -> bf16 weight conversion (all 4 weights, 1 launch) -
__global__ __launch_bounds__(256) void cvt_all_kernel(
    const float* __restrict__ qkvw, const float* __restrict__ projw,
    const float* __restrict__ fc1w, const float* __restrict__ fc2w,
    u16* __restrict__ wq, u16* __restrict__ wp,
    u16* __restrict__ w1, u16* __restrict__ w2) {
  int i = blockIdx.x * 256 + threadIdx.x;
  if (i < 442368) wq[i] = f2bf(qkvw[i]);
  else if (i < 589824) wp[i - 442368] = f2bf(projw[i - 442368]);
  else if (i < 1179648) w1[i - 589824] = f2bf(fc1w[i - 589824]);
  else if (i < 1769472) w2[i - 1179648] = f2bf(fc2w[i - 1179648]);
}

// ---------------- LayerNorm (fp32 in, bf16 out) ----------------------------
template <bool PERM>
__global__ __launch_bounds__(256) void ln_kernel(
    const float* __restrict__ x, const float* __restrict__ g,
    const float* __restrict__ bb, u16* __restrict__ xo) {
  int t = blockIdx.x * 4 + (threadIdx.x >> 6);
  int l = threadIdx.x & 63;
  int src = PERM ? win_to_orig(t) : t;
  const float* row = x + (size_t)src * 384;
  float v[6];
#pragma unroll
  for (int k = 0; k < 6; k++) v[k] = row[l + 64 * k];
  float s = 0.f;
#pragma unroll
  for (int k = 0; k < 6; k++) s += v[k];
#pragma unroll
  for (int d = 1; d < 64; d <<= 1) s += __shfl_xor(s, d);
  float mean = s * (1.f / 384.f);
  float q = 0.f;
#pragma unroll
  for (int k = 0; k < 6; k++) { float dv = v[k] - mean; q += dv * dv; }
#pragma unroll
  for (int d = 1; d < 64; d <<= 1) q += __shfl_xor(q, d);
  float rstd = rsqrtf(q * (1.f / 384.f) + 1e-5f);
  u16* orow = xo + (size_t)t * 384;
#pragma unroll
  for (int k = 0; k < 6; k++) {
    int c = l + 64 * k;
    orow[c] = f2bf((v[k] - mean) * rstd * g[c] + bb[c]);
  }
}

// ---------------- 128x128 BK=32 bf16 GEMM, B^T weights, dbuf prefetch ------
// EPI 0: +bias -> bf16                   (qkv)
// EPI 1: +bias +aux -> f32 at permuted row (proj + shortcut)
// EPI 2: +bias, GELU(tanh approx) -> bf16 (fc1)
// EPI 3: +bias +aux -> f32               (fc2 + residual, final output)
template <int EPI>
__global__ __launch_bounds__(256) void gemm_kernel(
    const u16* __restrict__ A, const u16* __restrict__ W,
    const float* __restrict__ bias, u16* __restrict__ outb,
    float* __restrict__ outf, const float* __restrict__ auxf,
    int K, int N, int NT) {
  __shared__ __align__(16) short As[8192];   // 2 x (128x32)
  __shared__ __align__(16) short Bs[8192];
  const int tid = threadIdx.x, wv = tid >> 6, l = tid & 63;
  const int lr = l & 15, lg = l >> 4;
  const int bm = blockIdx.x / NT, bn = blockIdx.x - bm * NT;
  const size_t m0 = (size_t)bm * 128, n0 = (size_t)bn * 128;
  // staging: lane l writes LDS shorts [wv*512 + l*8, +8) -> (row=wv*16+(l>>2),
  // chunk=l&3). Source chunk XOR-swizzled by ((row>>1)&3); LDS stays linear.
  const int prow = wv * 16 + (l >> 2);
  const int ccl = (((l & 3) ^ ((l >> 3) & 3)) << 3);
  const u16* ga0 = A + (m0 + prow) * K + ccl;
  const u16* ga1 = A + (m0 + 64 + prow) * K + ccl;
  const u16* gb0 = W + (n0 + prow) * K + ccl;
  const u16* gb1 = W + (n0 + 64 + prow) * K + ccl;
  const int stoff = wv * 512;
  const int wr = wv >> 1, wc = wv & 1;
  const int sw = (lr >> 1) & 3;  // read-side swizzle: (row>>1)&3 == (lr>>1)&3

#define STAGE(bufo, koff)                        \
  do {                                           \
    GLL16(ga0 + (koff), As + (bufo) + stoff);        \
    GLL16(ga1 + (koff), As + (bufo) + 2048 + stoff); \
    GLL16(gb0 + (koff), Bs + (bufo) + stoff);        \
    GLL16(gb1 + (koff), Bs + (bufo) + 2048 + stoff); \
  } while (0)

  f32x4 acc[4][4] = {};
  STAGE(0, 0);
  __syncthreads();                 // tile 0 resident
  int cur = 0;
  for (int k0 = 0; k0 < K; k0 += 32) {
    if (k0 + 32 < K) STAGE(cur ^ 4096, k0 + 32);   // prefetch next tile
    const short* as = As + cur;
    const short* bs = Bs + cur;
    s16x8 af[4], bfr[4];
#pragma unroll
    for (int mi = 0; mi < 4; mi++)
      af[mi] = *(const s16x8*)&as[(wr * 64 + mi * 16 + lr) * 32 + ((lg ^ sw) << 3)];
#pragma unroll
    for (int ni = 0; ni < 4; ni++)
      bfr[ni] = *(const s16x8*)&bs[(wc * 64 + ni * 16 + lr) * 32 + ((lg ^ sw) << 3)];
#pragma unroll
    for (int mi = 0; mi < 4; mi++)
#pragma unroll
      for (int ni = 0; ni < 4; ni++)
        acc[mi][ni] = mfma16(af[mi], bfr[ni], acc[mi][ni]);
    __syncthreads();               // drains prefetch (flew under MFMA phase)
    cur ^= 4096;
  }
#undef STAGE

  const int colb = (int)n0 + wc * 64;
#pragma unroll
  for (int mi = 0; mi < 4; mi++) {
#pragma unroll
    for (int r = 0; r < 4; r++) {
      const size_t m = m0 + wr * 64 + mi * 16 + lg * 4 + r;
      int dst = 0;
      if (EPI == 1) dst = win_to_orig((int)m);
#pragma unroll
      for (int ni = 0; ni < 4; ni++) {
        const int col = colb + ni * 16 + lr;
        float v = acc[mi][ni][r] + bias[col];
        if (EPI == 0) {
          outb[m * (size_t)N + col] = f2bf(v);
        } else if (EPI == 1) {
          outf[(size_t)dst * 384 + col] = v + auxf[(size_t)dst * 384 + col];
        } else if (EPI == 2) {
          // gelu(v) ~= v * sigmoid(2*0.79788456*(v + 0.044715 v^3))
          float u = v * (0.7978845608028654f + 0.0356774081f * v * v);
          float gl = v / (1.f + __expf(-2.f * u));
          outb[m * (size_t)N + col] = f2bf(gl);
        } else {
          outf[m * (size_t)N + col] = v + auxf[m * (size_t)N + col];
        }
      }
    }
  }
}

// ---------------- windowed attention: 1 wave per (window, head) ------------
// No V staging (direct L2 fragment loads); per-wave 16x76 P tile reused
// across the 4 row-tiles (softmax(mi) -> PV(mi) interleave).
__global__ __launch_bounds__(256) void attn_kernel(
    const u16* __restrict__ qkv, const float* __restrict__ rpb,
    const float* __restrict__ maskp, u16* __restrict__ out) {
  __shared__ __align__(16) short Pl[4][16 * 76];
  __shared__ float rpbs[169 * 12];
  const int tid = threadIdx.x, wv = tid >> 6, l = tid & 63;
  const int lr = l & 15, lg = l >> 4;
  for (int idx = tid; idx < 169 * 12; idx += 256) rpbs[idx] = rpb[idx];
  __syncthreads();

  const int task = blockIdx.x * 4 + wv;          // < 12288 exactly
  const int win = task / 12, h = task - win * 12;
  const int wi = win & 63;
  const short* base = (const short*)qkv + (size_t)win * 49 * 1152 + h * 32;

  // Q/K fragments (A-lane row = l&15, k-chunk = l>>4; rows >=49 zeroed)
  s16x8 qf[4], kf[4];
  const s16x8 zz = {0, 0, 0, 0, 0, 0, 0, 0};
#pragma unroll
  for (int mi = 0; mi < 4; mi++) {
    int n = mi * 16 + lr;
    if (n < 49) {
      qf[mi] = *(const s16x8*)(base + (size_t)n * 1152 + lg * 8);
      kf[mi] = *(const s16x8*)(base + (size_t)n * 1152 + 384 + lg * 8);
    } else { qf[mi] = zz; kf[mi] = zz; }
  }

  // S = Q K^T (padded 64x64), K=32 in one MFMA step
  f32x4 acc[4][4] = {};
#pragma unroll
  for (int mi = 0; mi < 4; mi++)
#pragma unroll
    for (int ni = 0; ni < 4; ni++)
      acc[mi][ni] = mfma16(qf[mi], kf[ni], acc[mi][ni]);

  // V B-fragments direct from global (L2-resident): vb[kk][nd][e] =
  // V[kk*32+lg*8+e][nd*16+lr]; issued now, latency hides under softmax.
  s16x8 vb[2][2];
#pragma unroll
  for (int kk = 0; kk < 2; kk++)
#pragma unroll
    for (int nd = 0; nd < 2; nd++)
#pragma unroll
      for (int e = 0; e < 8; e++) {
        int j = kk * 32 + lg * 8 + e;
        vb[kk][nd][e] = (j < 49)
            ? base[(size_t)j * 1152 + 768 + nd * 16 + lr] : (short)0;
      }

  short* pl = Pl[wv];
  // per row-tile mi: softmax 16 rows -> P tile in LDS -> PV -> store
#pragma unroll
  for (int mi = 0; mi < 4; mi++) {
    float rs[4];
#pragma unroll
    for (int r = 0; r < 4; r++) {
      const int irow = mi * 16 + lg * 4 + r;
      float sv[4];
      if (irow < 49) {
        const int yi = irow / 7, xi = irow - yi * 7;
        const float* mrow = maskp + ((size_t)wi * 49 + irow) * 49;
#pragma unroll
        for (int ni = 0; ni < 4; ni++) {
          const int j = ni * 16 + lr;
          if (j < 49) {
            int yj = j / 7, xj = j - yj * 7;
            int rpi = (yi - yj + 6) * 13 + (xi - xj + 6);
            sv[ni] = acc[mi][ni][r] * ATTN_SCALE + rpbs[rpi * 12 + h] + mrow[j];
          } else sv[ni] = -1e30f;
        }
      } else {
#pragma unroll
        for (int ni = 0; ni < 4; ni++) sv[ni] = -1e30f;
      }
      float mx = fmaxf(fmaxf(sv[0], sv[1]), fmaxf(sv[2], sv[3]));
#pragma unroll
      for (int d = 1; d < 16; d <<= 1) mx = fmaxf(mx, __shfl_xor(mx, d));
      float sm = 0.f;
#pragma unroll
      for (int ni = 0; ni < 4; ni++) { sv[ni] = __expf(sv[ni] - mx); sm += sv[ni]; }
#pragma unroll
      for (int d = 1; d < 16; d <<= 1) sm += __shfl_xor(sm, d);
      rs[r] = 1.f / sm;
#pragma unroll
      for (int ni = 0; ni < 4; ni++)
        pl[(lg * 4 + r) * 76 + ni * 16 + lr] = (short)f2bf(sv[ni]);
    }
    // PV for this row tile: A-frag row = lr within tile
    f32x4 o[2] = {{}, {}};
#pragma unroll
    for (int kk = 0; kk < 2; kk++) {
      s16x8 pa = *(const s16x8*)&pl[lr * 76 + kk * 32 + lg * 8];
#pragma unroll
      for (int nd = 0; nd < 2; nd++)
        o[nd] = mfma16(pa, vb[kk][nd], o[nd]);
    }
#pragma unroll
    for (int r = 0; r < 4; r++) {
      const int irow = mi * 16 + lg * 4 + r;
      if (irow < 49) {
#pragma unroll
        for (int nd = 0; nd < 2; nd++)
          out[((size_t)win * 49 + irow) * 384 + h * 32 + nd * 16 + lr] =
              f2bf(o[nd][r] * rs[r]);
      }
    }
  }
}

extern "C" void kernel_launch(void* const* d_in, const int* in_sizes, int n_in,
                              void* d_out, int out_size, void* d_ws, size_t ws_size,
                              hipStream_t stream) {
  (void)in_sizes; (void)n_in; (void)out_size; (void)ws_size;
  const float* x     = (const float*)d_in[0];
  const float* maskp = (const float*)d_in[1];
  const float* n1g   = (const float*)d_in[2];
  const float* n1b   = (const float*)d_in[3];
  const float* qkvw  = (const float*)d_in[4];
  const float* qkvb  = (const float*)d_in[5];
  const float* rpb   = (const float*)d_in[6];
  const float* projw = (const float*)d_in[7];
  const float* projb = (const float*)d_in[8];
  const float* n2g   = (const float*)d_in[9];
  const float* n2b   = (const float*)d_in[10];
  const float* fc1w  = (const float*)d_in[11];
  const float* fc1b  = (const float*)d_in[12];
  const float* fc2w  = (const float*)d_in[13];
  const float* fc2b  = (const float*)d_in[14];
  float* outp = (float*)d_out;

  char* ws = (char*)d_ws;
  u16*  regA = (u16*)ws;                           // qkv (50176x1152), then h2 chunks
  u16*  regB = (u16*)(ws + 115605504ull);          // xw / attn_out / xln2 (50176x384)
  float* xres = (float*)(ws + 154140672ull);       // fp32 residual (50176x384)
  u16*  wq = (u16*)(ws + 231211008ull);            // bf16 weights
  u16*  wp = wq + 442368;
  u16*  w1 = wp + 147456;
  u16*  w2 = w1 + 589824;                          // end: 234,749,952 B

  // 0. weights fp32 -> bf16 (single launch)
  cvt_all_kernel<<<6912, 256, 0, stream>>>(qkvw, projw, fc1w, fc2w, wq, wp, w1, w2);
  // 1. LN1 + cyclic shift + window partition (fp32 -> bf16, window order)
  ln_kernel<true><<<12544, 256, 0, stream>>>(x, n1g, n1b, regB);
  // 2. QKV projection: (50176x384) @ (384x1152)
  gemm_kernel<0><<<392 * 9, 256, 0, stream>>>(regB, wq, qkvb, regA, nullptr,
                                              nullptr, 384, 1152, 9);
  // 3. windowed attention
  attn_kernel<<<3072, 256, 0, stream>>>(regA, rpb, maskp, regB);
  // 4. output projection + shortcut, un-permute -> fp32 residual (orig order)
  gemm_kernel<1><<<392 * 3, 256, 0, stream>>>(regB, wp, projb, nullptr, xres,
                                              x, 384, 384, 3);
  // 5. LN2 (fp32 -> bf16)
  ln_kernel<false><<<12544, 256, 0, stream>>>(xres, n2g, n2b, regB);
  // 6/7. MLP in 2 M-chunks of 25088 rows (h2 reuses dead qkv region)
  for (int c = 0; c < 2; c++) {
    const u16* aln = regB + (size_t)c * 25088 * 384;
    float* oc = outp + (size_t)c * 25088 * 384;
    const float* rc = xres + (size_t)c * 25088 * 384;
    gemm_kernel<2><<<196 * 12, 256, 0, stream>>>(aln, w1, fc1b, regA, nullptr,
                                                 nullptr, 384, 1536, 12);
    gemm_kernel<3><<<196 * 3, 256, 0, stream>>>(regA, w2, fc2b, nullptr, oc,
                                                rc, 1536, 384, 3);
  }
}

// Round 4
// 514.767 us; speedup vs baseline: 1.1600x; 1.0875x over previous
//
#include <hip/hip_runtime.h>

typedef unsigned short u16;
typedef unsigned int u32;
typedef short s16x8 __attribute__((ext_vector_type(8)));
typedef float f32x4 __attribute__((ext_vector_type(4)));

#define ATTN_SCALE 0.17677669529663687f

__device__ __forceinline__ u16 f2bf(float f) {
  union { float f; u32 i; } c; c.f = f;
  u32 r = c.i + 0x7fffu + ((c.i >> 16) & 1u);
  return (u16)(r >> 16);
}
__device__ __forceinline__ float bf2f(u16 u) {
  union { u32 i; float f; } c; c.i = ((u32)u) << 16; return c.f;
}
__device__ __forceinline__ f32x4 mfma16(s16x8 a, s16x8 b, f32x4 c) {
  return __builtin_amdgcn_mfma_f32_16x16x32_bf16(a, b, c, 0, 0, 0);
}

typedef __attribute__((address_space(1))) u32 gas_u32;
typedef __attribute__((address_space(3))) u32 las_u32;
#define GLL16(gp, lp) __builtin_amdgcn_global_load_lds((gas_u32*)(gp), (las_u32*)(lp), 16, 0, 0)

// window-order token m -> original token index (same formula forward+reverse
// since roll(-3) partition and roll(+3) reverse both reduce to (p+3)%56).
__device__ __forceinline__ int win_to_orig(int m) {
  int b = m / 3136, rem = m - b * 3136;
  int w = rem / 49, n = rem - w * 49;
  int wh = w >> 3, ww = w & 7;
  int i = n / 7, j = n - i * 7;
  int r = wh * 7 + i + 3; if (r >= 56) r -= 56;
  int c = ww * 7 + j + 3; if (c >= 56) c -= 56;
  return b * 3136 + r * 56 + c;
}

// ---------------- fp32 -> bf16 weight conversion (all 4 weights, 1 launch) -
__global__ __launch_bounds__(256) void cvt_all_kernel(
    const float* __restrict__ qkvw, const float* __restrict__ projw,
    const float* __restrict__ fc1w, const float* __restrict__ fc2w,
    u16* __restrict__ wq, u16* __restrict__ wp,
    u16* __restrict__ w1, u16* __restrict__ w2) {
  int i = blockIdx.x * 256 + threadIdx.x;
  if (i < 442368) wq[i] = f2bf(qkvw[i]);
  else if (i < 589824) wp[i - 442368] = f2bf(projw[i - 442368]);
  else if (i < 1179648) w1[i - 589824] = f2bf(fc1w[i - 589824]);
  else if (i < 1769472) w2[i - 1179648] = f2bf(fc2w[i - 1179648]);
}

// ---------------- LayerNorm (fp32 or bf16 in, bf16 out) --------------------
template <bool PERM, bool BFIN>
__global__ __launch_bounds__(256) void ln_kernel(
    const void* __restrict__ xin, const float* __restrict__ g,
    const float* __restrict__ bb, u16* __restrict__ xo) {
  int t = blockIdx.x * 4 + (threadIdx.x >> 6);
  int l = threadIdx.x & 63;
  int src = PERM ? win_to_orig(t) : t;
  float v[6];
  if (BFIN) {
    const u16* row = (const u16*)xin + (size_t)src * 384;
#pragma unroll
    for (int k = 0; k < 6; k++) v[k] = bf2f(row[l + 64 * k]);
  } else {
    const float* row = (const float*)xin + (size_t)src * 384;
#pragma unroll
    for (int k = 0; k < 6; k++) v[k] = row[l + 64 * k];
  }
  float s = 0.f;
#pragma unroll
  for (int k = 0; k < 6; k++) s += v[k];
#pragma unroll
  for (int d = 1; d < 64; d <<= 1) s += __shfl_xor(s, d);
  float mean = s * (1.f / 384.f);
  float q = 0.f;
#pragma unroll
  for (int k = 0; k < 6; k++) { float dv = v[k] - mean; q += dv * dv; }
#pragma unroll
  for (int d = 1; d < 64; d <<= 1) q += __shfl_xor(q, d);
  float rstd = rsqrtf(q * (1.f / 384.f) + 1e-5f);
  u16* orow = xo + (size_t)t * 384;
#pragma unroll
  for (int k = 0; k < 6; k++) {
    int c = l + 64 * k;
    orow[c] = f2bf((v[k] - mean) * rstd * g[c] + bb[c]);
  }
}

// ---------------- 128x128 BK=32 bf16 GEMM, B^T weights, dbuf prefetch ------
// Grid is supertile-XCD-swizzled: d = st*(8*NT) + bn*8 + sub, so d%8 (the
// XCD) sees all NT column-blocks of one bm consecutively -> A-panel L2 reuse.
// EPI 0: +bias -> bf16                        (qkv)
// EPI 1: +bias +auxf[dst] -> bf16 at permuted row (proj + fp32-x shortcut)
// EPI 2: +bias, GELU(tanh approx) -> bf16     (fc1)
// EPI 3: +bias +bf16 auxb -> f32              (fc2 + residual, final output)
template <int EPI>
__global__ __launch_bounds__(256) void gemm_kernel(
    const u16* __restrict__ A, const u16* __restrict__ W,
    const float* __restrict__ bias, u16* __restrict__ outb,
    float* __restrict__ outf, const float* __restrict__ auxf,
    const u16* __restrict__ auxb, int K, int N, int NT, int NB) {
  __shared__ __align__(16) short As[8192];   // 2 x (128x32)
  __shared__ __align__(16) short Bs[8192];
  const int tid = threadIdx.x, wv = tid >> 6, l = tid & 63;
  const int lr = l & 15, lg = l >> 4;
  // supertile-XCD mapping (tail blocks linear when NB%8 != 0)
  int bm, bn;
  {
    const int STS = NT << 3;
    const int body = (NB >> 3) * STS;
    int d = blockIdx.x;
    if (d < body) {
      int st = d / STS, rem = d - st * STS;
      bn = rem >> 3;
      bm = st * 8 + (rem & 7);
    } else {
      int t = d - body;
      int tq = t / NT;
      bm = (NB & ~7) + tq;
      bn = t - tq * NT;
    }
  }
  const size_t m0 = (size_t)bm * 128, n0 = (size_t)bn * 128;
  // staging: lane l writes LDS shorts [wv*512 + l*8, +8) -> (row=wv*16+(l>>2),
  // chunk=l&3). Source chunk XOR-swizzled by ((row>>1)&3); LDS stays linear.
  const int prow = wv * 16 + (l >> 2);
  const int ccl = (((l & 3) ^ ((l >> 3) & 3)) << 3);
  const u16* ga0 = A + (m0 + prow) * K + ccl;
  const u16* ga1 = A + (m0 + 64 + prow) * K + ccl;
  const u16* gb0 = W + (n0 + prow) * K + ccl;
  const u16* gb1 = W + (n0 + 64 + prow) * K + ccl;
  const int stoff = wv * 512;
  const int wr = wv >> 1, wc = wv & 1;
  const int sw = (lr >> 1) & 3;  // read-side swizzle: (row>>1)&3 == (lr>>1)&3

#define STAGE(bufo, koff)                        \
  do {                                           \
    GLL16(ga0 + (koff), As + (bufo) + stoff);        \
    GLL16(ga1 + (koff), As + (bufo) + 2048 + stoff); \
    GLL16(gb0 + (koff), Bs + (bufo) + stoff);        \
    GLL16(gb1 + (koff), Bs + (bufo) + 2048 + stoff); \
  } while (0)

  f32x4 acc[4][4] = {};
  STAGE(0, 0);
  __syncthreads();                 // tile 0 resident
  int cur = 0;
  for (int k0 = 0; k0 < K; k0 += 32) {
    if (k0 + 32 < K) STAGE(cur ^ 4096, k0 + 32);   // prefetch next tile
    const short* as = As + cur;
    const short* bs = Bs + cur;
    s16x8 af[4], bfr[4];
#pragma unroll
    for (int mi = 0; mi < 4; mi++)
      af[mi] = *(const s16x8*)&as[(wr * 64 + mi * 16 + lr) * 32 + ((lg ^ sw) << 3)];
#pragma unroll
    for (int ni = 0; ni < 4; ni++)
      bfr[ni] = *(const s16x8*)&bs[(wc * 64 + ni * 16 + lr) * 32 + ((lg ^ sw) << 3)];
#pragma unroll
    for (int mi = 0; mi < 4; mi++)
#pragma unroll
      for (int ni = 0; ni < 4; ni++)
        acc[mi][ni] = mfma16(af[mi], bfr[ni], acc[mi][ni]);
    __syncthreads();               // drains prefetch (flew under MFMA phase)
    cur ^= 4096;
  }
#undef STAGE

  const int colb = (int)n0 + wc * 64;
#pragma unroll
  for (int mi = 0; mi < 4; mi++) {
#pragma unroll
    for (int r = 0; r < 4; r++) {
      const size_t m = m0 + wr * 64 + mi * 16 + lg * 4 + r;
      int dst = 0;
      if (EPI == 1) dst = win_to_orig((int)m);
#pragma unroll
      for (int ni = 0; ni < 4; ni++) {
        const int col = colb + ni * 16 + lr;
        float v = acc[mi][ni][r] + bias[col];
        if (EPI == 0) {
          outb[m * (size_t)N + col] = f2bf(v);
        } else if (EPI == 1) {
          outb[(size_t)dst * 384 + col] = f2bf(v + auxf[(size_t)dst * 384 + col]);
        } else if (EPI == 2) {
          // gelu(v) ~= v * sigmoid(2*0.79788456*(v + 0.044715 v^3))
          float u = v * (0.7978845608028654f + 0.0356774081f * v * v);
          float gl = v / (1.f + __expf(-2.f * u));
          outb[m * (size_t)N + col] = f2bf(gl);
        } else {
          outf[m * (size_t)N + col] = v + bf2f(auxb[m * (size_t)N + col]);
        }
      }
    }
  }
}

// ---------------- windowed attention: 1 wave per (window, head) ------------
// No V staging (direct L2 fragment loads); per-wave 16x76 P tile reused
// across the 4 row-tiles (softmax(mi) -> PV(mi) interleave).
__global__ __launch_bounds__(256) void attn_kernel(
    const u16* __restrict__ qkv, const float* __restrict__ rpb,
    const float* __restrict__ maskp, u16* __restrict__ out) {
  __shared__ __align__(16) short Pl[4][16 * 76];
  __shared__ float rpbs[169 * 12];
  const int tid = threadIdx.x, wv = tid >> 6, l = tid & 63;
  const int lr = l & 15, lg = l >> 4;
  for (int idx = tid; idx < 169 * 12; idx += 256) rpbs[idx] = rpb[idx];
  __syncthreads();

  const int task = blockIdx.x * 4 + wv;          // < 12288 exactly
  const int win = task / 12, h = task - win * 12;
  const int wi = win & 63;
  const short* base = (const short*)qkv + (size_t)win * 49 * 1152 + h * 32;

  // Q/K fragments (A-lane row = l&15, k-chunk = l>>4; rows >=49 zeroed)
  s16x8 qf[4], kf[4];
  const s16x8 zz = {0, 0, 0, 0, 0, 0, 0, 0};
#pragma unroll
  for (int mi = 0; mi < 4; mi++) {
    int n = mi * 16 + lr;
    if (n < 49) {
      qf[mi] = *(const s16x8*)(base + (size_t)n * 1152 + lg * 8);
      kf[mi] = *(const s16x8*)(base + (size_t)n * 1152 + 384 + lg * 8);
    } else { qf[mi] = zz; kf[mi] = zz; }
  }

  // S = Q K^T (padded 64x64), K=32 in one MFMA step
  f32x4 acc[4][4] = {};
#pragma unroll
  for (int mi = 0; mi < 4; mi++)
#pragma unroll
    for (int ni = 0; ni < 4; ni++)
      acc[mi][ni] = mfma16(qf[mi], kf[ni], acc[mi][ni]);

  // V B-fragments direct from global (L2-resident): vb[kk][nd][e] =
  // V[kk*32+lg*8+e][nd*16+lr]; issued now, latency hides under softmax.
  s16x8 vb[2][2];
#pragma unroll
  for (int kk = 0; kk < 2; kk++)
#pragma unroll
    for (int nd = 0; nd < 2; nd++)
#pragma unroll
      for (int e = 0; e < 8; e++) {
        int j = kk * 32 + lg * 8 + e;
        vb[kk][nd][e] = (j < 49)
            ? base[(size_t)j * 1152 + 768 + nd * 16 + lr] : (short)0;
      }

  short* pl = Pl[wv];
  // per row-tile mi: softmax 16 rows -> P tile in LDS -> PV -> store
#pragma unroll
  for (int mi = 0; mi < 4; mi++) {
    float rs[4];
#pragma unroll
    for (int r = 0; r < 4; r++) {
      const int irow = mi * 16 + lg * 4 + r;
      float sv[4];
      if (irow < 49) {
        const int yi = irow / 7, xi = irow - yi * 7;
        const float* mrow = maskp + ((size_t)wi * 49 + irow) * 49;
#pragma unroll
        for (int ni = 0; ni < 4; ni++) {
          const int j = ni * 16 + lr;
          if (j < 49) {
            int yj = j / 7, xj = j - yj * 7;
            int rpi = (yi - yj + 6) * 13 + (xi - xj + 6);
            sv[ni] = acc[mi][ni][r] * ATTN_SCALE + rpbs[rpi * 12 + h] + mrow[j];
          } else sv[ni] = -1e30f;
        }
      } else {
#pragma unroll
        for (int ni = 0; ni < 4; ni++) sv[ni] = -1e30f;
      }
      float mx = fmaxf(fmaxf(sv[0], sv[1]), fmaxf(sv[2], sv[3]));
#pragma unroll
      for (int d = 1; d < 16; d <<= 1) mx = fmaxf(mx, __shfl_xor(mx, d));
      float sm = 0.f;
#pragma unroll
      for (int ni = 0; ni < 4; ni++) { sv[ni] = __expf(sv[ni] - mx); sm += sv[ni]; }
#pragma unroll
      for (int d = 1; d < 16; d <<= 1) sm += __shfl_xor(sm, d);
      rs[r] = 1.f / sm;
#pragma unroll
      for (int ni = 0; ni < 4; ni++)
        pl[(lg * 4 + r) * 76 + ni * 16 + lr] = (short)f2bf(sv[ni]);
    }
    // PV for this row tile: A-frag row = lr within tile
    f32x4 o[2] = {{}, {}};
#pragma unroll
    for (int kk = 0; kk < 2; kk++) {
      s16x8 pa = *(const s16x8*)&pl[lr * 76 + kk * 32 + lg * 8];
#pragma unroll
      for (int nd = 0; nd < 2; nd++)
        o[nd] = mfma16(pa, vb[kk][nd], o[nd]);
    }
#pragma unroll
    for (int r = 0; r < 4; r++) {
      const int irow = mi * 16 + lg * 4 + r;
      if (irow < 49) {
#pragma unroll
        for (int nd = 0; nd < 2; nd++)
          out[((size_t)win * 49 + irow) * 384 + h * 32 + nd * 16 + lr] =
              f2bf(o[nd][r] * rs[r]);
      }
    }
  }
}

extern "C" void kernel_launch(void* const* d_in, const int* in_sizes, int n_in,
                              void* d_out, int out_size, void* d_ws, size_t ws_size,
                              hipStream_t stream) {
  (void)in_sizes; (void)n_in; (void)out_size; (void)ws_size;
  const float* x     = (const float*)d_in[0];
  const float* maskp = (const float*)d_in[1];
  const float* n1g   = (const float*)d_in[2];
  const float* n1b   = (const float*)d_in[3];
  const float* qkvw  = (const float*)d_in[4];
  const float* qkvb  = (const float*)d_in[5];
  const float* rpb   = (const float*)d_in[6];
  const float* projw = (const float*)d_in[7];
  const float* projb = (const float*)d_in[8];
  const float* n2g   = (const float*)d_in[9];
  const float* n2b   = (const float*)d_in[10];
  const float* fc1w  = (const float*)d_in[11];
  const float* fc1b  = (const float*)d_in[12];
  const float* fc2w  = (const float*)d_in[13];
  const float* fc2b  = (const float*)d_in[14];
  float* outp = (float*)d_out;

  char* ws = (char*)d_ws;
  u16*  regA  = (u16*)ws;                          // qkv (50176x1152), then h2 chunks
  u16*  regB  = (u16*)(ws + 115605504ull);         // xw / attn_out / xln2 (50176x384)
  u16*  xresb = (u16*)(ws + 154140672ull);         // bf16 residual (50176x384)
  u16*  wq = (u16*)(ws + 192675840ull);            // bf16 weights
  u16*  wp = wq + 442368;
  u16*  w1 = wp + 147456;
  u16*  w2 = w1 + 589824;                          // end: 196,214,784 B

  // 0. weights fp32 -> bf16 (single launch)
  cvt_all_kernel<<<6912, 256, 0, stream>>>(qkvw, projw, fc1w, fc2w, wq, wp, w1, w2);
  // 1. LN1 + cyclic shift + window partition (fp32 -> bf16, window order)
  ln_kernel<true, false><<<12544, 256, 0, stream>>>(x, n1g, n1b, regB);
  // 2. QKV projection: (50176x384) @ (384x1152)
  gemm_kernel<0><<<392 * 9, 256, 0, stream>>>(regB, wq, qkvb, regA, nullptr,
                                              nullptr, nullptr, 384, 1152, 9, 392);
  // 3. windowed attention
  attn_kernel<<<3072, 256, 0, stream>>>(regA, rpb, maskp, regB);
  // 4. output projection + fp32-x shortcut, un-permute -> bf16 residual
  gemm_kernel<1><<<392 * 3, 256, 0, stream>>>(regB, wp, projb, xresb, nullptr,
                                              x, nullptr, 384, 384, 3, 392);
  // 5. LN2 (bf16 -> bf16)
  ln_kernel<false, true><<<12544, 256, 0, stream>>>(xresb, n2g, n2b, regB);
  // 6/7. MLP in 2 M-chunks of 25088 rows (h2 reuses dead qkv region)
  for (int c = 0; c < 2; c++) {
    const u16* aln = regB + (size_t)c * 25088 * 384;
    float* oc = outp + (size_t)c * 25088 * 384;
    const u16* rc = xresb + (size_t)c * 25088 * 384;
    gemm_kernel<2><<<196 * 12, 256, 0, stream>>>(aln, w1, fc1b, regA, nullptr,
                                                 nullptr, nullptr, 384, 1536, 12, 196);
    gemm_kernel<3><<<196 * 3, 256, 0, stream>>>(regA, w2, fc2b, nullptr, oc,
                                                nullptr, rc, 1536, 384, 3, 196);
  }
}

// Round 5
// 437.847 us; speedup vs baseline: 1.3638x; 1.1757x over previous
//
#include <hip/hip_runtime.h>

typedef unsigned short u16;
typedef unsigned int u32;
typedef short s16x8 __attribute__((ext_vector_type(8)));
typedef float f32x4 __attribute__((ext_vector_type(4)));

#define ATTN_SCALE 0.17677669529663687f

__device__ __forceinline__ u16 f2bf(float f) {
  union { float f; u32 i; } c; c.f = f;
  u32 r = c.i + 0x7fffu + ((c.i >> 16) & 1u);
  return (u16)(r >> 16);
}
__device__ __forceinline__ float bf2f(u16 u) {
  union { u32 i; float f; } c; c.i = ((u32)u) << 16; return c.f;
}
__device__ __forceinline__ f32x4 mfma16(s16x8 a, s16x8 b, f32x4 c) {
  return __builtin_amdgcn_mfma_f32_16x16x32_bf16(a, b, c, 0, 0, 0);
}

typedef __attribute__((address_space(1))) u32 gas_u32;
typedef __attribute__((address_space(3))) u32 las_u32;
#define GLL16(gp, lp) __builtin_amdgcn_global_load_lds((gas_u32*)(gp), (las_u32*)(lp), 16, 0, 0)

// window-order token m -> original token index (same formula forward+reverse
// since roll(-3) partition and roll(+3) reverse both reduce to (p+3)%56).
__device__ __forceinline__ int win_to_orig(int m) {
  int b = m / 3136, rem = m - b * 3136;
  int w = rem / 49, n = rem - w * 49;
  int wh = w >> 3, ww = w & 7;
  int i = n / 7, j = n - i * 7;
  int r = wh * 7 + i + 3; if (r >= 56) r -= 56;
  int c = ww * 7 + j + 3; if (c >= 56) c -= 56;
  return b * 3136 + r * 56 + c;
}

// ---------------- fp32 -> bf16 weight conversion (all 4 weights, 1 launch) -
__global__ __launch_bounds__(256) void cvt_all_kernel(
    const float* __restrict__ qkvw, const float* __restrict__ projw,
    const float* __restrict__ fc1w, const float* __restrict__ fc2w,
    u16* __restrict__ wq, u16* __restrict__ wp,
    u16* __restrict__ w1, u16* __restrict__ w2) {
  int i = blockIdx.x * 256 + threadIdx.x;
  if (i < 442368) wq[i] = f2bf(qkvw[i]);
  else if (i < 589824) wp[i - 442368] = f2bf(projw[i - 442368]);
  else if (i < 1179648) w1[i - 589824] = f2bf(fc1w[i - 589824]);
  else if (i < 1769472) w2[i - 1179648] = f2bf(fc2w[i - 1179648]);
}

// ---------------- LayerNorm (fp32 or bf16 in, bf16 out) --------------------
template <bool PERM, bool BFIN>
__global__ __launch_bounds__(256) void ln_kernel(
    const void* __restrict__ xin, const float* __restrict__ g,
    const float* __restrict__ bb, u16* __restrict__ xo) {
  int t = blockIdx.x * 4 + (threadIdx.x >> 6);
  int l = threadIdx.x & 63;
  int src = PERM ? win_to_orig(t) : t;
  float v[6];
  if (BFIN) {
    const u16* row = (const u16*)xin + (size_t)src * 384;
#pragma unroll
    for (int k = 0; k < 6; k++) v[k] = bf2f(row[l + 64 * k]);
  } else {
    const float* row = (const float*)xin + (size_t)src * 384;
#pragma unroll
    for (int k = 0; k < 6; k++) v[k] = row[l + 64 * k];
  }
  float s = 0.f;
#pragma unroll
  for (int k = 0; k < 6; k++) s += v[k];
#pragma unroll
  for (int d = 1; d < 64; d <<= 1) s += __shfl_xor(s, d);
  float mean = s * (1.f / 384.f);
  float q = 0.f;
#pragma unroll
  for (int k = 0; k < 6; k++) { float dv = v[k] - mean; q += dv * dv; }
#pragma unroll
  for (int d = 1; d < 64; d <<= 1) q += __shfl_xor(q, d);
  float rstd = rsqrtf(q * (1.f / 384.f) + 1e-5f);
  u16* orow = xo + (size_t)t * 384;
#pragma unroll
  for (int k = 0; k < 6; k++) {
    int c = l + 64 * k;
    orow[c] = f2bf((v[k] - mean) * rstd * g[c] + bb[c]);
  }
}

// ---------------- 128x128 BK=32 bf16 GEMM, B^T weights ---------------------
// 2-tile-deep pipeline, counted vmcnt (T3+T4): loads get ~2 iterations to
// fly; vmcnt never drains to 0 in the main loop. Raw barriers (no
// __syncthreads drain). Grid supertile-XCD-swizzled (T1).
// EPI 0: +bias -> bf16                        (qkv)
// EPI 1: +bias +auxf[dst] -> bf16 at permuted row (proj + fp32-x shortcut)
// EPI 2: +bias, GELU(tanh approx) -> bf16     (fc1)
// EPI 3: +bias +bf16 auxb -> f32              (fc2 + residual, final output)
template <int EPI>
__global__ __launch_bounds__(256) void gemm_kernel(
    const u16* __restrict__ A, const u16* __restrict__ W,
    const float* __restrict__ bias, u16* __restrict__ outb,
    float* __restrict__ outf, const float* __restrict__ auxf,
    const u16* __restrict__ auxb, int K, int N, int NT, int NB) {
  __shared__ __align__(16) short As[8192];   // 2 x (128x32)
  __shared__ __align__(16) short Bs[8192];
  const int tid = threadIdx.x, wv = tid >> 6, l = tid & 63;
  const int lr = l & 15, lg = l >> 4;
  // supertile-XCD mapping (tail blocks linear when NB%8 != 0)
  int bm, bn;
  {
    const int STS = NT << 3;
    const int body = (NB >> 3) * STS;
    int d = blockIdx.x;
    if (d < body) {
      int st = d / STS, rem = d - st * STS;
      bn = rem >> 3;
      bm = st * 8 + (rem & 7);
    } else {
      int t = d - body;
      int tq = t / NT;
      bm = (NB & ~7) + tq;
      bn = t - tq * NT;
    }
  }
  const size_t m0 = (size_t)bm * 128, n0 = (size_t)bn * 128;
  // staging: lane l writes LDS shorts [wv*512 + l*8, +8) -> (row=wv*16+(l>>2),
  // chunk=l&3). Source chunk XOR-swizzled by ((row>>1)&3); LDS stays linear.
  const int prow = wv * 16 + (l >> 2);
  const int ccl = (((l & 3) ^ ((l >> 3) & 3)) << 3);
  const u16* ga0 = A + (m0 + prow) * K + ccl;
  const u16* ga1 = A + (m0 + 64 + prow) * K + ccl;
  const u16* gb0 = W + (n0 + prow) * K + ccl;
  const u16* gb1 = W + (n0 + 64 + prow) * K + ccl;
  const int stoff = wv * 512;
  const int wr = wv >> 1, wc = wv & 1;
  const int sw = (lr >> 1) & 3;  // read-side swizzle: (row>>1)&3 == (lr>>1)&3
  const int aoff = (wr * 64 + lr) * 32 + ((lg ^ sw) << 3);
  const int boff = (wc * 64 + lr) * 32 + ((lg ^ sw) << 3);

#define STAGE(bufo, koff)                            \
  do {                                               \
    GLL16(ga0 + (koff), As + (bufo) + stoff);        \
    GLL16(ga1 + (koff), As + (bufo) + 2048 + stoff); \
    GLL16(gb0 + (koff), Bs + (bufo) + stoff);        \
    GLL16(gb1 + (koff), Bs + (bufo) + 2048 + stoff); \
  } while (0)
#define FRAG_READS(cur)                                              \
  do {                                                               \
    const short* as = As + (cur);                                    \
    const short* bs = Bs + (cur);                                    \
    _Pragma("unroll") for (int mi = 0; mi < 4; mi++)                 \
        af[mi] = *(const s16x8*)&as[aoff + mi * (16 * 32)];          \
    _Pragma("unroll") for (int ni = 0; ni < 4; ni++)                 \
        bfr[ni] = *(const s16x8*)&bs[boff + ni * (16 * 32)];         \
  } while (0)
#define MFMA_TILE()                                        \
  do {                                                     \
    _Pragma("unroll") for (int mi = 0; mi < 4; mi++)       \
        _Pragma("unroll") for (int ni = 0; ni < 4; ni++)   \
            acc[mi][ni] = mfma16(af[mi], bfr[ni], acc[mi][ni]); \
  } while (0)

  f32x4 acc[4][4] = {};
  s16x8 af[4], bfr[4];
  STAGE(0, 0);
  STAGE(4096, 32);                      // 8 loads in flight
  int cur = 0;
  int k0 = 0;
  for (; k0 < K - 32; k0 += 32) {
    // own 4 loads of tile(cur) done; next tile's 4 may remain in flight
    asm volatile("s_waitcnt vmcnt(4)" ::: "memory");
    __builtin_amdgcn_sched_barrier(0);
    __builtin_amdgcn_s_barrier();       // all waves' tile(cur) data in LDS
    FRAG_READS(cur);
    asm volatile("s_waitcnt lgkmcnt(0)" ::: "memory");
    __builtin_amdgcn_sched_barrier(0);
    __builtin_amdgcn_s_barrier();       // all waves done reading buf(cur)
    if (k0 + 64 < K) STAGE(cur, k0 + 64);  // refill just-read buffer
    MFMA_TILE();
    cur ^= 4096;
  }
  // peeled last tile: nothing newer in flight -> drain to 0
  asm volatile("s_waitcnt vmcnt(0)" ::: "memory");
  __builtin_amdgcn_sched_barrier(0);
  __builtin_amdgcn_s_barrier();
  FRAG_READS(cur);
  asm volatile("s_waitcnt lgkmcnt(0)" ::: "memory");
  __builtin_amdgcn_sched_barrier(0);
  MFMA_TILE();
#undef STAGE
#undef FRAG_READS
#undef MFMA_TILE

  const int colb = (int)n0 + wc * 64;
#pragma unroll
  for (int mi = 0; mi < 4; mi++) {
#pragma unroll
    for (int r = 0; r < 4; r++) {
      const size_t m = m0 + wr * 64 + mi * 16 + lg * 4 + r;
      int dst = 0;
      if (EPI == 1) dst = win_to_orig((int)m);
#pragma unroll
      for (int ni = 0; ni < 4; ni++) {
        const int col = colb + ni * 16 + lr;
        float v = acc[mi][ni][r] + bias[col];
        if (EPI == 0) {
          outb[m * (size_t)N + col] = f2bf(v);
        } else if (EPI == 1) {
          outb[(size_t)dst * 384 + col] = f2bf(v + auxf[(size_t)dst * 384 + col]);
        } else if (EPI == 2) {
          // gelu(v) ~= v * sigmoid(2*0.79788456*(v + 0.044715 v^3))
          float u = v * (0.7978845608028654f + 0.0356774081f * v * v);
          float gl = v / (1.f + __expf(-2.f * u));
          outb[m * (size_t)N + col] = f2bf(gl);
        } else {
          outf[m * (size_t)N + col] = v + bf2f(auxb[m * (size_t)N + col]);
        }
      }
    }
  }
}

// ---------------- windowed attention: 1 wave per (window, head) ------------
// No V staging (direct L2 fragment loads); per-wave 16x76 P tile reused
// across the 4 row-tiles (softmax(mi) -> PV(mi) interleave).
__global__ __launch_bounds__(256) void attn_kernel(
    const u16* __restrict__ qkv, const float* __restrict__ rpb,
    const float* __restrict__ maskp, u16* __restrict__ out) {
  __shared__ __align__(16) short Pl[4][16 * 76];
  __shared__ float rpbs[169 * 12];
  const int tid = threadIdx.x, wv = tid >> 6, l = tid & 63;
  const int lr = l & 15, lg = l >> 4;
  for (int idx = tid; idx < 169 * 12; idx += 256) rpbs[idx] = rpb[idx];
  __syncthreads();

  const int task = blockIdx.x * 4 + wv;          // < 12288 exactly
  const int win = task / 12, h = task - win * 12;
  const int wi = win & 63;
  const short* base = (const short*)qkv + (size_t)win * 49 * 1152 + h * 32;

  // Q/K fragments (A-lane row = l&15, k-chunk = l>>4; rows >=49 zeroed)
  s16x8 qf[4], kf[4];
  const s16x8 zz = {0, 0, 0, 0, 0, 0, 0, 0};
#pragma unroll
  for (int mi = 0; mi < 4; mi++) {
    int n = mi * 16 + lr;
    if (n < 49) {
      qf[mi] = *(const s16x8*)(base + (size_t)n * 1152 + lg * 8);
      kf[mi] = *(const s16x8*)(base + (size_t)n * 1152 + 384 + lg * 8);
    } else { qf[mi] = zz; kf[mi] = zz; }
  }

  // S = Q K^T (padded 64x64), K=32 in one MFMA step
  f32x4 acc[4][4] = {};
#pragma unroll
  for (int mi = 0; mi < 4; mi++)
#pragma unroll
    for (int ni = 0; ni < 4; ni++)
      acc[mi][ni] = mfma16(qf[mi], kf[ni], acc[mi][ni]);

  // V B-fragments direct from global (L2-resident): vb[kk][nd][e] =
  // V[kk*32+lg*8+e][nd*16+lr]; issued now, latency hides under softmax.
  s16x8 vb[2][2];
#pragma unroll
  for (int kk = 0; kk < 2; kk++)
#pragma unroll
    for (int nd = 0; nd < 2; nd++)
#pragma unroll
      for (int e = 0; e < 8; e++) {
        int j = kk * 32 + lg * 8 + e;
        vb[kk][nd][e] = (j < 49)
            ? base[(size_t)j * 1152 + 768 + nd * 16 + lr] : (short)0;
      }

  short* pl = Pl[wv];
  // per row-tile mi: softmax 16 rows -> P tile in LDS -> PV -> store
#pragma unroll
  for (int mi = 0; mi < 4; mi++) {
    float rs[4];
#pragma unroll
    for (int r = 0; r < 4; r++) {
      const int irow = mi * 16 + lg * 4 + r;
      float sv[4];
      if (irow < 49) {
        const int yi = irow / 7, xi = irow - yi * 7;
        const float* mrow = maskp + ((size_t)wi * 49 + irow) * 49;
#pragma unroll
        for (int ni = 0; ni < 4; ni++) {
          const int j = ni * 16 + lr;
          if (j < 49) {
            int yj = j / 7, xj = j - yj * 7;
            int rpi = (yi - yj + 6) * 13 + (xi - xj + 6);
            sv[ni] = acc[mi][ni][r] * ATTN_SCALE + rpbs[rpi * 12 + h] + mrow[j];
          } else sv[ni] = -1e30f;
        }
      } else {
#pragma unroll
        for (int ni = 0; ni < 4; ni++) sv[ni] = -1e30f;
      }
      float mx = fmaxf(fmaxf(sv[0], sv[1]), fmaxf(sv[2], sv[3]));
#pragma unroll
      for (int d = 1; d < 16; d <<= 1) mx = fmaxf(mx, __shfl_xor(mx, d));
      float sm = 0.f;
#pragma unroll
      for (int ni = 0; ni < 4; ni++) { sv[ni] = __expf(sv[ni] - mx); sm += sv[ni]; }
#pragma unroll
      for (int d = 1; d < 16; d <<= 1) sm += __shfl_xor(sm, d);
      rs[r] = 1.f / sm;
#pragma unroll
      for (int ni = 0; ni < 4; ni++)
        pl[(lg * 4 + r) * 76 + ni * 16 + lr] = (short)f2bf(sv[ni]);
    }
    // PV for this row tile: A-frag row = lr within tile
    f32x4 o[2] = {{}, {}};
#pragma unroll
    for (int kk = 0; kk < 2; kk++) {
      s16x8 pa = *(const s16x8*)&pl[lr * 76 + kk * 32 + lg * 8];
#pragma unroll
      for (int nd = 0; nd < 2; nd++)
        o[nd] = mfma16(pa, vb[kk][nd], o[nd]);
    }
#pragma unroll
    for (int r = 0; r < 4; r++) {
      const int irow = mi * 16 + lg * 4 + r;
      if (irow < 49) {
#pragma unroll
        for (int nd = 0; nd < 2; nd++)
          out[((size_t)win * 49 + irow) * 384 + h * 32 + nd * 16 + lr] =
              f2bf(o[nd][r] * rs[r]);
      }
    }
  }
}

extern "C" void kernel_launch(void* const* d_in, const int* in_sizes, int n_in,
                              void* d_out, int out_size, void* d_ws, size_t ws_size,
                              hipStream_t stream) {
  (void)in_sizes; (void)n_in; (void)out_size; (void)ws_size;
  const float* x     = (const float*)d_in[0];
  const float* maskp = (const float*)d_in[1];
  const float* n1g   = (const float*)d_in[2];
  const float* n1b   = (const float*)d_in[3];
  const float* qkvw  = (const float*)d_in[4];
  const float* qkvb  = (const float*)d_in[5];
  const float* rpb   = (const float*)d_in[6];
  const float* projw = (const float*)d_in[7];
  const float* projb = (const float*)d_in[8];
  const float* n2g   = (const float*)d_in[9];
  const float* n2b   = (const float*)d_in[10];
  const float* fc1w  = (const float*)d_in[11];
  const float* fc1b  = (const float*)d_in[12];
  const float* fc2w  = (const float*)d_in[13];
  const float* fc2b  = (const float*)d_in[14];
  float* outp = (float*)d_out;

  char* ws = (char*)d_ws;
  u16*  regA  = (u16*)ws;                          // qkv (50176x1152), then h2 chunks
  u16*  regB  = (u16*)(ws + 115605504ull);         // xw / attn_out / xln2 (50176x384)
  u16*  xresb = (u16*)(ws + 154140672ull);         // bf16 residual (50176x384)
  u16*  wq = (u16*)(ws + 192675840ull);            // bf16 weights
  u16*  wp = wq + 442368;
  u16*  w1 = wp + 147456;
  u16*  w2 = w1 + 589824;                          // end: 196,214,784 B

  // 0. weights fp32 -> bf16 (single launch)
  cvt_all_kernel<<<6912, 256, 0, stream>>>(qkvw, projw, fc1w, fc2w, wq, wp, w1, w2);
  // 1. LN1 + cyclic shift + window partition (fp32 -> bf16, window order)
  ln_kernel<true, false><<<12544, 256, 0, stream>>>(x, n1g, n1b, regB);
  // 2. QKV projection: (50176x384) @ (384x1152)
  gemm_kernel<0><<<392 * 9, 256, 0, stream>>>(regB, wq, qkvb, regA, nullptr,
                                              nullptr, nullptr, 384, 1152, 9, 392);
  // 3. windowed attention
  attn_kernel<<<3072, 256, 0, stream>>>(regA, rpb, maskp, regB);
  // 4. output projection + fp32-x shortcut, un-permute -> bf16 residual
  gemm_kernel<1><<<392 * 3, 256, 0, stream>>>(regB, wp, projb, xresb, nullptr,
                                              x, nullptr, 384, 384, 3, 392);
  // 5. LN2 (bf16 -> bf16)
  ln_kernel<false, true><<<12544, 256, 0, stream>>>(xresb, n2g, n2b, regB);
  // 6/7. MLP in 2 M-chunks of 25088 rows (h2 reuses dead qkv region)
  for (int c = 0; c < 2; c++) {
    const u16* aln = regB + (size_t)c * 25088 * 384;
    float* oc = outp + (size_t)c * 25088 * 384;
    const u16* rc = xresb + (size_t)c * 25088 * 384;
    gemm_kernel<2><<<196 * 12, 256, 0, stream>>>(aln, w1, fc1b, regA, nullptr,
                                                 nullptr, nullptr, 384, 1536, 12, 196);
    gemm_kernel<3><<<196 * 3, 256, 0, stream>>>(regA, w2, fc2b, nullptr, oc,
                                                nullptr, rc, 1536, 384, 3, 196);
  }
}

// Round 6
// 409.399 us; speedup vs baseline: 1.4586x; 1.0695x over previous
//
#include <hip/hip_runtime.h>

typedef unsigned short u16;
typedef unsigned int u32;
typedef short s16x8 __attribute__((ext_vector_type(8)));
typedef unsigned short u16x4 __attribute__((ext_vector_type(4)));
typedef float f32x4 __attribute__((ext_vector_type(4)));

#define ATTN_SCALE 0.17677669529663687f

__device__ __forceinline__ u16 f2bf(float f) {
  union { float f; u32 i; } c; c.f = f;
  u32 r = c.i + 0x7fffu + ((c.i >> 16) & 1u);
  return (u16)(r >> 16);
}
__device__ __forceinline__ float bf2f(u16 u) {
  union { u32 i; float f; } c; c.i = ((u32)u) << 16; return c.f;
}
__device__ __forceinline__ f32x4 mfma16(s16x8 a, s16x8 b, f32x4 c) {
  return __builtin_amdgcn_mfma_f32_16x16x32_bf16(a, b, c, 0, 0, 0);
}

typedef __attribute__((address_space(1))) u32 gas_u32;
typedef __attribute__((address_space(3))) u32 las_u32;
#define GLL16(gp, lp) __builtin_amdgcn_global_load_lds((gas_u32*)(gp), (las_u32*)(lp), 16, 0, 0)

// window-order token m -> original token index (same formula forward+reverse
// since roll(-3) partition and roll(+3) reverse both reduce to (p+3)%56).
__device__ __forceinline__ int win_to_orig(int m) {
  int b = m / 3136, rem = m - b * 3136;
  int w = rem / 49, n = rem - w * 49;
  int wh = w >> 3, ww = w & 7;
  int i = n / 7, j = n - i * 7;
  int r = wh * 7 + i + 3; if (r >= 56) r -= 56;
  int c = ww * 7 + j + 3; if (c >= 56) c -= 56;
  return b * 3136 + r * 56 + c;
}

// ---------------- fp32 -> bf16 weight conversion (all 4 weights, 1 launch) -
__global__ __launch_bounds__(256) void cvt_all_kernel(
    const float* __restrict__ qkvw, const float* __restrict__ projw,
    const float* __restrict__ fc1w, const float* __restrict__ fc2w,
    u16* __restrict__ wq, u16* __restrict__ wp,
    u16* __restrict__ w1, u16* __restrict__ w2) {
  int i = blockIdx.x * 256 + threadIdx.x;
  if (i < 442368) wq[i] = f2bf(qkvw[i]);
  else if (i < 589824) wp[i - 442368] = f2bf(projw[i - 442368]);
  else if (i < 1179648) w1[i - 589824] = f2bf(fc1w[i - 589824]);
  else if (i < 1769472) w2[i - 1179648] = f2bf(fc2w[i - 1179648]);
}

// ---------------- bias+mask table: tbl[wi][h][irow 64][lr 16][ni 4] --------
// element (irow, lr, ni) = rpb[rpi(irow, j)]+mask[wi][irow][j], j=ni*16+lr;
// -1e30 on pads. Collapses the per-element softmax addressing to one load.
__global__ __launch_bounds__(256) void mk_tbl_kernel(
    const float* __restrict__ rpb, const float* __restrict__ maskp,
    u16* __restrict__ tbl) {
  int idx = blockIdx.x * 256 + threadIdx.x;   // (wi*12+h)*4096 + irow*64 + lr*4 + ni
  int wh = idx >> 12;
  int rem = idx & 4095;
  int irow = rem >> 6;
  int lr = (rem >> 2) & 15, ni = rem & 3;
  int j = ni * 16 + lr;
  int wi = wh / 12, h = wh - wi * 12;
  float val = -1e30f;
  if (irow < 49 && j < 49) {
    int yi = irow / 7, xi = irow - yi * 7;
    int yj = j / 7, xj = j - yj * 7;
    int rpi = (yi - yj + 6) * 13 + (xi - xj + 6);
    val = rpb[rpi * 12 + h] + maskp[((size_t)wi * 49 + irow) * 49 + j];
  }
  tbl[idx] = f2bf(val);
}

// ---------------- LayerNorm (fp32 or bf16 in, bf16 out) --------------------
template <bool PERM, bool BFIN>
__global__ __launch_bounds__(256) void ln_kernel(
    const void* __restrict__ xin, const float* __restrict__ g,
    const float* __restrict__ bb, u16* __restrict__ xo) {
  int t = blockIdx.x * 4 + (threadIdx.x >> 6);
  int l = threadIdx.x & 63;
  int src = PERM ? win_to_orig(t) : t;
  float v[6];
  if (BFIN) {
    const u16* row = (const u16*)xin + (size_t)src * 384;
#pragma unroll
    for (int k = 0; k < 6; k++) v[k] = bf2f(row[l + 64 * k]);
  } else {
    const float* row = (const float*)xin + (size_t)src * 384;
#pragma unroll
    for (int k = 0; k < 6; k++) v[k] = row[l + 64 * k];
  }
  float s = 0.f;
#pragma unroll
  for (int k = 0; k < 6; k++) s += v[k];
#pragma unroll
  for (int d = 1; d < 64; d <<= 1) s += __shfl_xor(s, d);
  float mean = s * (1.f / 384.f);
  float q = 0.f;
#pragma unroll
  for (int k = 0; k < 6; k++) { float dv = v[k] - mean; q += dv * dv; }
#pragma unroll
  for (int d = 1; d < 64; d <<= 1) q += __shfl_xor(q, d);
  float rstd = rsqrtf(q * (1.f / 384.f) + 1e-5f);
  u16* orow = xo + (size_t)t * 384;
#pragma unroll
  for (int k = 0; k < 6; k++) {
    int c = l + 64 * k;
    orow[c] = f2bf((v[k] - mean) * rstd * g[c] + bb[c]);
  }
}

// ---------------- 128x128 BK=32 bf16 GEMM, B^T weights ---------------------
// 2-tile-deep pipeline, counted vmcnt (T3+T4); supertile-XCD swizzle (T1).
// EPI 0: +bias -> bf16                        (qkv)
// EPI 1: +bias +auxf[dst] -> bf16 at permuted row (proj + fp32-x shortcut)
// EPI 2: +bias, GELU(tanh approx) -> bf16     (fc1)
// EPI 3: +bias +bf16 auxb -> f32              (fc2 + residual, final output)
template <int EPI>
__global__ __launch_bounds__(256) void gemm_kernel(
    const u16* __restrict__ A, const u16* __restrict__ W,
    const float* __restrict__ bias, u16* __restrict__ outb,
    float* __restrict__ outf, const float* __restrict__ auxf,
    const u16* __restrict__ auxb, int K, int N, int NT, int NB) {
  __shared__ __align__(16) short As[8192];   // 2 x (128x32)
  __shared__ __align__(16) short Bs[8192];
  const int tid = threadIdx.x, wv = tid >> 6, l = tid & 63;
  const int lr = l & 15, lg = l >> 4;
  // supertile-XCD mapping (tail blocks linear when NB%8 != 0)
  int bm, bn;
  {
    const int STS = NT << 3;
    const int body = (NB >> 3) * STS;
    int d = blockIdx.x;
    if (d < body) {
      int st = d / STS, rem = d - st * STS;
      bn = rem >> 3;
      bm = st * 8 + (rem & 7);
    } else {
      int t = d - body;
      int tq = t / NT;
      bm = (NB & ~7) + tq;
      bn = t - tq * NT;
    }
  }
  const size_t m0 = (size_t)bm * 128, n0 = (size_t)bn * 128;
  // staging: lane l writes LDS shorts [wv*512 + l*8, +8) -> (row=wv*16+(l>>2),
  // chunk=l&3). Source chunk XOR-swizzled by ((row>>1)&3); LDS stays linear.
  const int prow = wv * 16 + (l >> 2);
  const int ccl = (((l & 3) ^ ((l >> 3) & 3)) << 3);
  const u16* ga0 = A + (m0 + prow) * K + ccl;
  const u16* ga1 = A + (m0 + 64 + prow) * K + ccl;
  const u16* gb0 = W + (n0 + prow) * K + ccl;
  const u16* gb1 = W + (n0 + 64 + prow) * K + ccl;
  const int stoff = wv * 512;
  const int wr = wv >> 1, wc = wv & 1;
  const int sw = (lr >> 1) & 3;  // read-side swizzle: (row>>1)&3 == (lr>>1)&3
  const int aoff = (wr * 64 + lr) * 32 + ((lg ^ sw) << 3);
  const int boff = (wc * 64 + lr) * 32 + ((lg ^ sw) << 3);

#define STAGE(bufo, koff)                            \
  do {                                               \
    GLL16(ga0 + (koff), As + (bufo) + stoff);        \
    GLL16(ga1 + (koff), As + (bufo) + 2048 + stoff); \
    GLL16(gb0 + (koff), Bs + (bufo) + stoff);        \
    GLL16(gb1 + (koff), Bs + (bufo) + 2048 + stoff); \
  } while (0)
#define FRAG_READS(cur)                                              \
  do {                                                               \
    const short* as = As + (cur);                                    \
    const short* bs = Bs + (cur);                                    \
    _Pragma("unroll") for (int mi = 0; mi < 4; mi++)                 \
        af[mi] = *(const s16x8*)&as[aoff + mi * (16 * 32)];          \
    _Pragma("unroll") for (int ni = 0; ni < 4; ni++)                 \
        bfr[ni] = *(const s16x8*)&bs[boff + ni * (16 * 32)];         \
  } while (0)
#define MFMA_TILE()                                        \
  do {                                                     \
    _Pragma("unroll") for (int mi = 0; mi < 4; mi++)       \
        _Pragma("unroll") for (int ni = 0; ni < 4; ni++)   \
            acc[mi][ni] = mfma16(af[mi], bfr[ni], acc[mi][ni]); \
  } while (0)

  f32x4 acc[4][4] = {};
  s16x8 af[4], bfr[4];
  STAGE(0, 0);
  STAGE(4096, 32);                      // 8 loads in flight
  int cur = 0;
  int k0 = 0;
  for (; k0 < K - 32; k0 += 32) {
    // own 4 loads of tile(cur) done; next tile's 4 may remain in flight
    asm volatile("s_waitcnt vmcnt(4)" ::: "memory");
    __builtin_amdgcn_sched_barrier(0);
    __builtin_amdgcn_s_barrier();       // all waves' tile(cur) data in LDS
    FRAG_READS(cur);
    asm volatile("s_waitcnt lgkmcnt(0)" ::: "memory");
    __builtin_amdgcn_sched_barrier(0);
    __builtin_amdgcn_s_barrier();       // all waves done reading buf(cur)
    if (k0 + 64 < K) STAGE(cur, k0 + 64);  // refill just-read buffer
    MFMA_TILE();
    cur ^= 4096;
  }
  // peeled last tile: nothing newer in flight -> drain to 0
  asm volatile("s_waitcnt vmcnt(0)" ::: "memory");
  __builtin_amdgcn_sched_barrier(0);
  __builtin_amdgcn_s_barrier();
  FRAG_READS(cur);
  asm volatile("s_waitcnt lgkmcnt(0)" ::: "memory");
  __builtin_amdgcn_sched_barrier(0);
  MFMA_TILE();
#undef STAGE
#undef FRAG_READS
#undef MFMA_TILE

  const int colb = (int)n0 + wc * 64;
#pragma unroll
  for (int mi = 0; mi < 4; mi++) {
#pragma unroll
    for (int r = 0; r < 4; r++) {
      const size_t m = m0 + wr * 64 + mi * 16 + lg * 4 + r;
      int dst = 0;
      if (EPI == 1) dst = win_to_orig((int)m);
#pragma unroll
      for (int ni = 0; ni < 4; ni++) {
        const int col = colb + ni * 16 + lr;
        float v = acc[mi][ni][r] + bias[col];
        if (EPI == 0) {
          outb[m * (size_t)N + col] = f2bf(v);
        } else if (EPI == 1) {
          outb[(size_t)dst * 384 + col] = f2bf(v + auxf[(size_t)dst * 384 + col]);
        } else if (EPI == 2) {
          // gelu(v) ~= v * sigmoid(2*0.79788456*(v + 0.044715 v^3))
          float u = v * (0.7978845608028654f + 0.0356774081f * v * v);
          float gl = v / (1.f + __expf(-2.f * u));
          outb[m * (size_t)N + col] = f2bf(gl);
        } else {
          outf[m * (size_t)N + col] = v + bf2f(auxb[m * (size_t)N + col]);
        }
      }
    }
  }
}

// ---------------- windowed attention: 1 wave per (window, head) ------------
// Combined bias+mask table (no /7 chains, no scattered mask loads, no
// in-softmax branches); V fragments direct from L2 (pads multiply P==0);
// per-wave 16x76 P tile; no block-level synchronization at all.
__global__ __launch_bounds__(256) void attn_kernel(
    const u16* __restrict__ qkv, const u16* __restrict__ tbl,
    u16* __restrict__ out) {
  __shared__ __align__(16) short Pl[4][16 * 76];
  const int tid = threadIdx.x, wv = tid >> 6, l = tid & 63;
  const int lr = l & 15, lg = l >> 4;

  const int task = blockIdx.x * 4 + wv;          // < 12288 exactly
  const int win = task / 12, h = task - win * 12;
  const int wi = win & 63;
  const short* base = (const short*)qkv + (size_t)win * 49 * 1152 + h * 32;
  const u16* tb = tbl + (size_t)(wi * 12 + h) * 4096 + lr * 4;

  // Q/K fragments (A-lane row = l&15, k-chunk = l>>4; rows >=49 zeroed --
  // K garbage could overflow to inf in QK^T, so the zero-pad stays)
  s16x8 qf[4], kf[4];
  const s16x8 zz = {0, 0, 0, 0, 0, 0, 0, 0};
#pragma unroll
  for (int mi = 0; mi < 4; mi++) {
    int n = mi * 16 + lr;
    if (n < 49) {
      qf[mi] = *(const s16x8*)(base + (size_t)n * 1152 + lg * 8);
      kf[mi] = *(const s16x8*)(base + (size_t)n * 1152 + 384 + lg * 8);
    } else { qf[mi] = zz; kf[mi] = zz; }
  }
  // V B-fragments direct from global (L2-resident); pad rows j>=49 read
  // adjacent finite bf16 data and are multiplied by P==0 exactly.
  s16x8 vb[2][2];
#pragma unroll
  for (int kk = 0; kk < 2; kk++)
#pragma unroll
    for (int nd = 0; nd < 2; nd++)
#pragma unroll
      for (int e = 0; e < 8; e++)
        vb[kk][nd][e] = base[(size_t)(kk * 32 + lg * 8 + e) * 1152 + 768 + nd * 16 + lr];
  // bias+mask table, tile 0 (rest software-pipelined one mi ahead)
  u16x4 t4[4][4];
#pragma unroll
  for (int r = 0; r < 4; r++)
    t4[0][r] = *(const u16x4*)&tb[(lg * 4 + r) * 64];

  // S = Q K^T (padded 64x64), K=32 in one MFMA step
  f32x4 acc[4][4] = {};
  __builtin_amdgcn_s_setprio(1);
#pragma unroll
  for (int mi = 0; mi < 4; mi++)
#pragma unroll
    for (int ni = 0; ni < 4; ni++)
      acc[mi][ni] = mfma16(qf[mi], kf[ni], acc[mi][ni]);
  __builtin_amdgcn_s_setprio(0);

  short* pl = Pl[wv];
  // per row-tile mi: softmax 16 rows -> P tile in LDS -> PV -> store
#pragma unroll
  for (int mi = 0; mi < 4; mi++) {
    if (mi < 3) {   // prefetch next tile's table rows (latency hides here)
#pragma unroll
      for (int r = 0; r < 4; r++)
        t4[mi + 1][r] = *(const u16x4*)&tb[((mi + 1) * 16 + lg * 4 + r) * 64];
    }
    float rs[4];
#pragma unroll
    for (int r = 0; r < 4; r++) {
      float sv[4];
#pragma unroll
      for (int ni = 0; ni < 4; ni++)
        sv[ni] = acc[mi][ni][r] * ATTN_SCALE + bf2f(t4[mi][r][ni]);
      float mx = fmaxf(fmaxf(sv[0], sv[1]), fmaxf(sv[2], sv[3]));
#pragma unroll
      for (int d = 1; d < 16; d <<= 1) mx = fmaxf(mx, __shfl_xor(mx, d));
      float sm = 0.f;
#pragma unroll
      for (int ni = 0; ni < 4; ni++) { sv[ni] = __expf(sv[ni] - mx); sm += sv[ni]; }
#pragma unroll
      for (int d = 1; d < 16; d <<= 1) sm += __shfl_xor(sm, d);
      rs[r] = 1.f / sm;
#pragma unroll
      for (int ni = 0; ni < 4; ni++)
        pl[(lg * 4 + r) * 76 + ni * 16 + lr] = (short)f2bf(sv[ni]);
    }
    // PV for this row tile: A-frag row = lr within tile
    f32x4 o[2] = {{}, {}};
    __builtin_amdgcn_s_setprio(1);
#pragma unroll
    for (int kk = 0; kk < 2; kk++) {
      s16x8 pa = *(const s16x8*)&pl[lr * 76 + kk * 32 + lg * 8];
#pragma unroll
      for (int nd = 0; nd < 2; nd++)
        o[nd] = mfma16(pa, vb[kk][nd], o[nd]);
    }
    __builtin_amdgcn_s_setprio(0);
#pragma unroll
    for (int r = 0; r < 4; r++) {
      const int irow = mi * 16 + lg * 4 + r;
      if (irow < 49) {
#pragma unroll
        for (int nd = 0; nd < 2; nd++)
          out[((size_t)win * 49 + irow) * 384 + h * 32 + nd * 16 + lr] =
              f2bf(o[nd][r] * rs[r]);
      }
    }
  }
}

extern "C" void kernel_launch(void* const* d_in, const int* in_sizes, int n_in,
                              void* d_out, int out_size, void* d_ws, size_t ws_size,
                              hipStream_t stream) {
  (void)in_sizes; (void)n_in; (void)out_size; (void)ws_size;
  const float* x     = (const float*)d_in[0];
  const float* maskp = (const float*)d_in[1];
  const float* n1g   = (const float*)d_in[2];
  const float* n1b   = (const float*)d_in[3];
  const float* qkvw  = (const float*)d_in[4];
  const float* qkvb  = (const float*)d_in[5];
  const float* rpb   = (const float*)d_in[6];
  const float* projw = (const float*)d_in[7];
  const float* projb = (const float*)d_in[8];
  const float* n2g   = (const float*)d_in[9];
  const float* n2b   = (const float*)d_in[10];
  const float* fc1w  = (const float*)d_in[11];
  const float* fc1b  = (const float*)d_in[12];
  const float* fc2w  = (const float*)d_in[13];
  const float* fc2b  = (const float*)d_in[14];
  float* outp = (float*)d_out;

  char* ws = (char*)d_ws;
  u16*  regA  = (u16*)ws;                          // qkv (50176x1152), then h2 chunks
  u16*  regB  = (u16*)(ws + 115605504ull);         // xw / attn_out / xln2 (50176x384)
  u16*  xresb = (u16*)(ws + 154140672ull);         // bf16 residual (50176x384)
  u16*  wq = (u16*)(ws + 192675840ull);            // bf16 weights
  u16*  wp = wq + 442368;
  u16*  w1 = wp + 147456;
  u16*  w2 = w1 + 589824;
  u16*  tbl = w2 + 589824;                         // 6.29 MB; end ~202.5 MB

  // 0. weights fp32 -> bf16 + bias/mask table
  cvt_all_kernel<<<6912, 256, 0, stream>>>(qkvw, projw, fc1w, fc2w, wq, wp, w1, w2);
  mk_tbl_kernel<<<12288, 256, 0, stream>>>(rpb, maskp, tbl);
  // 1. LN1 + cyclic shift + window partition (fp32 -> bf16, window order)
  ln_kernel<true, false><<<12544, 256, 0, stream>>>(x, n1g, n1b, regB);
  // 2. QKV projection: (50176x384) @ (384x1152)
  gemm_kernel<0><<<392 * 9, 256, 0, stream>>>(regB, wq, qkvb, regA, nullptr,
                                              nullptr, nullptr, 384, 1152, 9, 392);
  // 3. windowed attention
  attn_kernel<<<3072, 256, 0, stream>>>(regA, tbl, regB);
  // 4. output projection + fp32-x shortcut, un-permute -> bf16 residual
  gemm_kernel<1><<<392 * 3, 256, 0, stream>>>(regB, wp, projb, xresb, nullptr,
                                              x, nullptr, 384, 384, 3, 392);
  // 5. LN2 (bf16 -> bf16)
  ln_kernel<false, true><<<12544, 256, 0, stream>>>(xresb, n2g, n2b, regB);
  // 6/7. MLP in 2 M-chunks of 25088 rows (h2 reuses dead qkv region)
  for (int c = 0; c < 2; c++) {
    const u16* aln = regB + (size_t)c * 25088 * 384;
    float* oc = outp + (size_t)c * 25088 * 384;
    const u16* rc = xresb + (size_t)c * 25088 * 384;
    gemm_kernel<2><<<196 * 12, 256, 0, stream>>>(aln, w1, fc1b, regA, nullptr,
                                                 nullptr, nullptr, 384, 1536, 12, 196);
    gemm_kernel<3><<<196 * 3, 256, 0, stream>>>(regA, w2, fc2b, nullptr, oc,
                                                nullptr, rc, 1536, 384, 3, 196);
  }
}